// Round 23
// baseline (80.990 us; speedup 1.0000x reference)
//
#include <hip/hip_runtime.h>
#include <hip/hip_bf16.h>
#include <math.h>

typedef __attribute__((ext_vector_type(8))) short bf16x8;
typedef __attribute__((ext_vector_type(4))) float f32x4;
typedef unsigned short u16;

__device__ __forceinline__ unsigned short f2bf(float f) {
    unsigned u = __builtin_bit_cast(unsigned, f);
    u += 0x7fffu + ((u >> 16) & 1u);          // round-to-nearest-even
    return (unsigned short)(u >> 16);
}
__device__ __forceinline__ float bf2f(unsigned short v) {
    return __builtin_bit_cast(float, (unsigned)v << 16);
}
// compiler-native conversion (1-2 ops vs 3-4 for the bit-twiddle; RNE)
__device__ __forceinline__ unsigned short f2bf_n(float f) {
    __hip_bfloat16 h = __float2bfloat16(f);
    return __builtin_bit_cast(unsigned short, h);
}

// ---------------------------------------------------------------------------
// Prep (proven): 384 blocks, one wave each. Build row r of mesh s via
// register+shuffle composition, sincos inline with 4-deep mzi prefetch.
// P1: [256 cols][128 k]; P2,P3: [256 cols][256 k], block-16 re/im layout.
// ---------------------------------------------------------------------------
__global__ __launch_bounds__(128) void prep_all_kernel(
    const float* __restrict__ mzi1, const float* __restrict__ mzi2,
    const float* __restrict__ mzi3, const float* __restrict__ inph,
    const float* __restrict__ outph1, const float* __restrict__ outph2,
    const float* __restrict__ outph3,
    u16* __restrict__ P1, u16* __restrict__ P2, u16* __restrict__ P3)
{
    const int b = blockIdx.x, t = threadIdx.x;
    if (t >= 64) return;               // one wave per block

    const int s = b >> 7, r = b & 127;
    const float* mzi = (s == 0) ? mzi1 : ((s == 1) ? mzi2 : mzi3);

    float2 a = make_float2(0.f, 0.f), b2 = make_float2(0.f, 0.f);
    if (s == 0) {
        float sp, cp; __sincosf(inph[r], &sp, &cp);
        if (2 * t == r)     a  = make_float2(cp, sp);
        if (2 * t + 1 == r) b2 = make_float2(cp, sp);
    } else {
        if (2 * t == r)     a.x  = 1.f;
        if (2 * t + 1 == r) b2.x = 1.f;
    }

    auto ldmz = [&](int L) -> float2 {
        const int start = L & 1;
        const int m = 64 - start;
        if (t < m) {
            const int off = (L >> 1) * 254 + start * 128 + 2 * t;
            return *(const float2*)(mzi + off);
        }
        return make_float2(0.f, 0.f);
    };
    float2 mz[4];
    #pragma unroll
    for (int i = 0; i < 4; ++i) mz[i] = ldmz(i);

    #pragma unroll 4
    for (int L = 0; L < 128; ++L) {
        const float2 v = mz[L & 3];
        if (L < 124) mz[L & 3] = ldmz(L + 4);
        float st, ct, sp, cp;
        __sincosf(v.x, &st, &ct);
        __sincosf(v.y, &sp, &cp);
        if ((L & 1) == 0) {
            float pr = ct * (a.x * cp - a.y * sp) + st * b2.x;
            float pi = ct * (a.x * sp + a.y * cp) + st * b2.y;
            float qr = st * a.x - ct * (b2.x * cp + b2.y * sp);
            float qi = st * a.y - ct * (b2.y * cp - b2.x * sp);
            a = make_float2(pr, pi); b2 = make_float2(qr, qi);
        } else {
            float2 an;
            an.x = __shfl_down(a.x, 1); an.y = __shfl_down(a.y, 1);
            float pr = ct * (b2.x * cp - b2.y * sp) + st * an.x;
            float pi = ct * (b2.x * sp + b2.y * cp) + st * an.y;
            float qr = st * b2.x - ct * (an.x * cp + an.y * sp);
            float qi = st * b2.y - ct * (an.y * cp - an.x * sp);
            if (t < 63) b2 = make_float2(pr, pi);
            float2 qs;
            qs.x = __shfl_up(qr, 1); qs.y = __shfl_up(qi, 1);
            if (t >= 1) a = qs;
        }
    }

    const float* outph = (s == 0) ? outph1 : ((s == 1) ? outph2 : outph3);
    #pragma unroll
    for (int h = 0; h < 2; ++h) {
        const int j = 2 * t + h;
        float2 w = h ? b2 : a;
        float sp, cp; __sincosf(outph[j], &sp, &cp);
        const float wr = w.x * cp - w.y * sp;
        const float wi = w.x * sp + w.y * cp;
        const int cre = ((j >> 4) * 32) + (j & 15);
        if (s == 0) {
            P1[cre * 128 + r]        = f2bf(wr);
            P1[(cre + 16) * 128 + r] = f2bf(wi);
        } else {
            u16* P = (s == 1) ? P2 : P3;
            const int rre = ((r >> 4) * 32) + (r & 15);
            P[cre * 256 + rre]             = f2bf(wr);
            P[cre * 256 + rre + 16]        = f2bf(-wi);
            P[(cre + 16) * 256 + rre]      = f2bf(wi);
            P[(cre + 16) * 256 + rre + 16] = f2bf(wr);
        }
    }
}

// ---------------------------------------------------------------------------
// Combine (R22-proven, ~2-3us): P34[n][k] = sum_c P3[c*256+k] * Wval(n,c).
// Thread t of block n -> (cs = t>>5, kb = (t&31)*8): 32 x {bf16x8 P3 read +
// lane-uniform W read + 8 fmaf}; 8-way LDS reduce over cs + bf16 pack.
// ---------------------------------------------------------------------------
__global__ __launch_bounds__(256) void combine_kernel(
    const u16* __restrict__ P3, const float* __restrict__ W,
    u16* __restrict__ P34)
{
    __shared__ float partial[8][256];
    const int n  = blockIdx.x;     // 0..127 output col
    const int t  = threadIdx.x;
    const int cs = t >> 5;         // 0..7 c-slice
    const int kb = (t & 31) * 8;   // k base

    float acc[8];
    #pragma unroll
    for (int e = 0; e < 8; ++e) acc[e] = 0.f;

    #pragma unroll 4
    for (int cc = 0; cc < 32; ++cc) {
        const int c = cs * 32 + cc;
        const int j = (cc < 16) ? (cs * 16 + cc) : (128 + cs * 16 + (cc - 16));
        const float w = W[n * 256 + j];
        bf16x8 p = *(const bf16x8*)&P3[c * 256 + kb];
        #pragma unroll
        for (int e = 0; e < 8; ++e)
            acc[e] = fmaf(bf2f((unsigned short)p[e]), w, acc[e]);
    }

    #pragma unroll
    for (int e = 0; e < 8; ++e) partial[cs][kb + e] = acc[e];
    __syncthreads();

    if (cs == 0) {
        #pragma unroll
        for (int e = 0; e < 8; ++e) {
            float s = 0.f;
            #pragma unroll
            for (int q = 0; q < 8; ++q) s += partial[q][kb + e];
            P34[n * 256 + kb + e] = f2bf(s);
        }
    }
}

// ---------------------------------------------------------------------------
// Main fused kernel. R23 = R22 structure (512 threads = 8 narrow waves
// 1M x 8N, wave tile 64x32, 64 rows/block, unroll-2 k-loops, dbuf 2x32KB,
// (512,4), spill-free) + two micro-opts:
//  (a) native bf16 converts (f2bf_n) in all hot paths: 1-2 ops vs 3-4,
//      ~112 converts/wave -> VALU (busiest pipe, 31%) trimmed.
//  (b) cross-barrier B-prefetch: first 2 k-steps of stage-2's P2 frags
//      (16 regs) issued during nofu1, and of final's P34 frags (8 regs)
//      during nofu2 -> nofu VALU covers the ~300cyc L2 latency, removing
//      the post-barrier bubble. Peak regs ~76+32=108 < 128: no spill.
// ---------------------------------------------------------------------------
__global__ __launch_bounds__(512, 4) void ficonn_mfma_kernel(
    const float* __restrict__ x,
    const u16* __restrict__ P1, const u16* __restrict__ P2,
    const u16* __restrict__ P34,
    const float* __restrict__ al1, const float* __restrict__ be1,
    const float* __restrict__ al2, const float* __restrict__ be2,
    const float* __restrict__ bias, float* __restrict__ out)
{
    __shared__ __align__(16) char zBuf[2][32768];  // [64 rows][256 cols] bf16, swizzled
    char* const z0 = zBuf[0];
    char* const z1 = zBuf[1];

    const int tid  = threadIdx.x;
    const int lane = tid & 63;
    const int wv   = tid >> 6;        // 0..7 (N-split)
    const int l16  = lane & 15;
    const int kg   = lane >> 4;
    const int nb   = wv * 32;         // col base, stages 1-2
    const size_t rowBase = (size_t)blockIdx.x * 64;

    const int jf = wv * 16 + l16;     // this thread's complex feature
    const float av1 = 0.5f * fminf(fmaxf(al1[jf], 0.f), 10.f);
    const float bv1 = fminf(fmaxf(be1[jf], 0.f), 10.f);
    const float av2 = 0.5f * fminf(fmaxf(al2[jf], 0.f), 10.f);
    const float bv2 = fminf(fmaxf(be2[jf], 0.f), 10.f);

    // ---- stage x tile (64 rows x 128 cols fp32) into z0 as bf16, coalesced --
    {
        const float4* xg = (const float4*)(x + rowBase * 128);
        #pragma unroll
        for (int i = 0; i < 4; ++i) {
            const int idx = tid + i * 512;        // 0..2047
            const int row = idx >> 5;             // 32 float4 per row
            const int c4  = idx & 31;
            float4 f = xg[idx];
            uint2 v;
            v.x = (unsigned)f2bf_n(f.x) | ((unsigned)f2bf_n(f.y) << 16);
            v.y = (unsigned)f2bf_n(f.z) | ((unsigned)f2bf_n(f.w) << 16);
            const unsigned byte = ((unsigned)(row * 512 + c4 * 8)) ^ ((unsigned)(row & 31) << 4);
            *(uint2*)(z0 + byte) = v;
        }
    }
    __syncthreads();    // B1: x staged in z0

    f32x4 acc[4][2];

    // ================= stage 1: read z0 (x), B = P1, K=128 -> write z1 ======
    #pragma unroll
    for (int mt = 0; mt < 4; ++mt)
        #pragma unroll
        for (int nt = 0; nt < 2; ++nt) acc[mt][nt] = (f32x4){0.f, 0.f, 0.f, 0.f};

    #pragma unroll 2
    for (int ksl = 0; ksl < 4; ++ksl) {
        const int k0 = ksl * 32 + kg * 8;
        bf16x8 A[4];
        #pragma unroll
        for (int mt = 0; mt < 4; ++mt) {
            const int row = mt * 16 + l16;
            const unsigned byte = ((unsigned)(row * 512 + k0 * 2)) ^ ((unsigned)(row & 31) << 4);
            A[mt] = *(const bf16x8*)(z0 + byte);
        }
        #pragma unroll
        for (int nt = 0; nt < 2; ++nt) {
            bf16x8 Bf = *(const bf16x8*)&P1[(nb + nt * 16 + l16) * 128 + k0];
            #pragma unroll
            for (int mt = 0; mt < 4; ++mt)
                acc[mt][nt] = __builtin_amdgcn_mfma_f32_16x16x32_bf16(A[mt], Bf, acc[mt][nt], 0, 0, 0);
        }
    }

    // prefetch stage-2 B frags (ks=0,1) — in flight across nofu1 + B2
    bf16x8 Bpre[4];
    #pragma unroll
    for (int ks = 0; ks < 2; ++ks)
        #pragma unroll
        for (int nt = 0; nt < 2; ++nt)
            Bpre[ks * 2 + nt] = *(const bf16x8*)&P2[(nb + nt * 16 + l16) * 256 + ks * 32 + kg * 8];

    // nofu1 + store to z1 (different buffer: no pre-barrier)
    #pragma unroll
    for (int mt = 0; mt < 4; ++mt)
        #pragma unroll
        for (int r = 0; r < 4; ++r) {
            float re = acc[mt][0][r], im = acc[mt][1][r];
            float I = fmaf(re, re, fmaf(im, im, 1e-8f));
            float fct = __expf(__fdividef(-av1, fmaf(bv1, I, 1.f)));
            re *= fct; im *= fct;
            const int row = mt * 16 + kg * 4 + r;
            const int colRe = nb + l16;
            const unsigned sw = (unsigned)(row & 31) << 4;
            *(u16*)(z1 + (((unsigned)(row * 512 + colRe * 2)) ^ sw)) = f2bf_n(re);
            *(u16*)(z1 + (((unsigned)(row * 512 + (colRe + 16) * 2)) ^ sw)) = f2bf_n(im);
        }
    __syncthreads();    // B2: z1 complete

    // ================= stage 2: read z1, B = P2, K=256 -> write z0 ==========
    #pragma unroll
    for (int mt = 0; mt < 4; ++mt)
        #pragma unroll
        for (int nt = 0; nt < 2; ++nt) acc[mt][nt] = (f32x4){0.f, 0.f, 0.f, 0.f};

    #pragma unroll 2
    for (int ks = 0; ks < 8; ++ks) {
        const int k0 = ks * 32 + kg * 8;
        bf16x8 A[4];
        #pragma unroll
        for (int mt = 0; mt < 4; ++mt) {
            const int row = mt * 16 + l16;
            const unsigned byte = ((unsigned)(row * 512 + k0 * 2)) ^ ((unsigned)(row & 31) << 4);
            A[mt] = *(const bf16x8*)(z1 + byte);
        }
        #pragma unroll
        for (int nt = 0; nt < 2; ++nt) {
            bf16x8 Bf = (ks < 2) ? Bpre[ks * 2 + nt]
                                 : *(const bf16x8*)&P2[(nb + nt * 16 + l16) * 256 + k0];
            #pragma unroll
            for (int mt = 0; mt < 4; ++mt)
                acc[mt][nt] = __builtin_amdgcn_mfma_f32_16x16x32_bf16(A[mt], Bf, acc[mt][nt], 0, 0, 0);
        }
    }

    // prefetch final-stage B frags (ks=0,1) — in flight across nofu2 + B3
    bf16x8 BpreF[2];
    {
        const int nb2p = wv * 16;
        #pragma unroll
        for (int ks = 0; ks < 2; ++ks)
            BpreF[ks] = *(const bf16x8*)&P34[(nb2p + l16) * 256 + ks * 32 + kg * 8];
    }

    // nofu2 + store to z0
    #pragma unroll
    for (int mt = 0; mt < 4; ++mt)
        #pragma unroll
        for (int r = 0; r < 4; ++r) {
            float re = acc[mt][0][r], im = acc[mt][1][r];
            float I = fmaf(re, re, fmaf(im, im, 1e-8f));
            float fct = __expf(__fdividef(-av2, fmaf(bv2, I, 1.f)));
            re *= fct; im *= fct;
            const int row = mt * 16 + kg * 4 + r;
            const int colRe = nb + l16;
            const unsigned sw = (unsigned)(row & 31) << 4;
            *(u16*)(z0 + (((unsigned)(row * 512 + colRe * 2)) ^ sw)) = f2bf_n(re);
            *(u16*)(z0 + (((unsigned)(row * 512 + (colRe + 16) * 2)) ^ sw)) = f2bf_n(im);
        }
    __syncthreads();    // B3: z0 complete

    // ================= final: read z0, B = P34 [128 cols][256 k] ============
    f32x4 facc[4];
    #pragma unroll
    for (int mt = 0; mt < 4; ++mt) facc[mt] = (f32x4){0.f, 0.f, 0.f, 0.f};

    const int nb2 = wv * 16;
    #pragma unroll 2
    for (int ks = 0; ks < 8; ++ks) {
        const int k0 = ks * 32 + kg * 8;
        bf16x8 A[4];
        #pragma unroll
        for (int mt = 0; mt < 4; ++mt) {
            const int row = mt * 16 + l16;
            const unsigned byte = ((unsigned)(row * 512 + k0 * 2)) ^ ((unsigned)(row & 31) << 4);
            A[mt] = *(const bf16x8*)(z0 + byte);
        }
        bf16x8 Bf = (ks < 2) ? BpreF[ks]
                             : *(const bf16x8*)&P34[(nb2 + l16) * 256 + k0];
        #pragma unroll
        for (int mt = 0; mt < 4; ++mt)
            facc[mt] = __builtin_amdgcn_mfma_f32_16x16x32_bf16(A[mt], Bf, facc[mt], 0, 0, 0);
    }

    const float bcol = bias[nb2 + l16];
    #pragma unroll
    for (int mt = 0; mt < 4; ++mt)
        #pragma unroll
        for (int r = 0; r < 4; ++r) {
            const size_t row = rowBase + mt * 16 + kg * 4 + r;
            out[row * 128 + nb2 + l16] = facc[mt][r] + bcol;
        }
}

extern "C" void kernel_launch(void* const* d_in, const int* in_sizes, int n_in,
                              void* d_out, int out_size, void* d_ws, size_t ws_size,
                              hipStream_t stream)
{
    const float* x      = (const float*)d_in[0];
    const float* inph   = (const float*)d_in[1];
    const float* mzi1   = (const float*)d_in[2];
    const float* outph1 = (const float*)d_in[3];
    const float* alpha1 = (const float*)d_in[4];
    const float* beta1  = (const float*)d_in[5];
    const float* mzi2   = (const float*)d_in[6];
    const float* outph2 = (const float*)d_in[7];
    const float* alpha2 = (const float*)d_in[8];
    const float* beta2  = (const float*)d_in[9];
    const float* mzi3   = (const float*)d_in[10];
    const float* outph3 = (const float*)d_in[11];
    const float* W      = (const float*)d_in[12];
    const float* bias   = (const float*)d_in[13];

    const int B = in_sizes[0] / 128;

    // ws layout: P1 64KB | P2 128KB | P3 128KB | P34 64KB = 384KB
    u16* P1  = (u16*)d_ws;
    u16* P2  = P1 + 32768;
    u16* P3  = P2 + 65536;
    u16* P34 = P3 + 65536;

    prep_all_kernel<<<384, 128, 0, stream>>>(
        mzi1, mzi2, mzi3, inph, outph1, outph2, outph3, P1, P2, P3);
    combine_kernel<<<128, 256, 0, stream>>>(P3, W, P34);
    ficonn_mfma_kernel<<<B / 64, 512, 0, stream>>>(
        x, P1, P2, P34, alpha1, beta1, alpha2, beta2, bias, (float*)d_out);
}

// Round 24
// 75.389 us; speedup vs baseline: 1.0743x; 1.0743x over previous
//
#include <hip/hip_runtime.h>
#include <math.h>

typedef __attribute__((ext_vector_type(8))) short bf16x8;
typedef __attribute__((ext_vector_type(4))) float f32x4;
typedef unsigned short u16;

__device__ __forceinline__ unsigned short f2bf(float f) {
    unsigned u = __builtin_bit_cast(unsigned, f);
    u += 0x7fffu + ((u >> 16) & 1u);          // round-to-nearest-even
    return (unsigned short)(u >> 16);
}
__device__ __forceinline__ float bf2f(unsigned short v) {
    return __builtin_bit_cast(float, (unsigned)v << 16);
}

// ---------------------------------------------------------------------------
// Prep (proven): 384 blocks, one wave each. Build row r of mesh s via
// register+shuffle composition, sincos inline with 4-deep mzi prefetch.
// P1: [256 cols][128 k]; P2,P3: [256 cols][256 k], block-16 re/im layout.
// ---------------------------------------------------------------------------
__global__ __launch_bounds__(128) void prep_all_kernel(
    const float* __restrict__ mzi1, const float* __restrict__ mzi2,
    const float* __restrict__ mzi3, const float* __restrict__ inph,
    const float* __restrict__ outph1, const float* __restrict__ outph2,
    const float* __restrict__ outph3,
    u16* __restrict__ P1, u16* __restrict__ P2, u16* __restrict__ P3)
{
    const int b = blockIdx.x, t = threadIdx.x;
    if (t >= 64) return;               // one wave per block

    const int s = b >> 7, r = b & 127;
    const float* mzi = (s == 0) ? mzi1 : ((s == 1) ? mzi2 : mzi3);

    float2 a = make_float2(0.f, 0.f), b2 = make_float2(0.f, 0.f);
    if (s == 0) {
        float sp, cp; __sincosf(inph[r], &sp, &cp);
        if (2 * t == r)     a  = make_float2(cp, sp);
        if (2 * t + 1 == r) b2 = make_float2(cp, sp);
    } else {
        if (2 * t == r)     a.x  = 1.f;
        if (2 * t + 1 == r) b2.x = 1.f;
    }

    auto ldmz = [&](int L) -> float2 {
        const int start = L & 1;
        const int m = 64 - start;
        if (t < m) {
            const int off = (L >> 1) * 254 + start * 128 + 2 * t;
            return *(const float2*)(mzi + off);
        }
        return make_float2(0.f, 0.f);
    };
    float2 mz[4];
    #pragma unroll
    for (int i = 0; i < 4; ++i) mz[i] = ldmz(i);

    #pragma unroll 4
    for (int L = 0; L < 128; ++L) {
        const float2 v = mz[L & 3];
        if (L < 124) mz[L & 3] = ldmz(L + 4);
        float st, ct, sp, cp;
        __sincosf(v.x, &st, &ct);
        __sincosf(v.y, &sp, &cp);
        if ((L & 1) == 0) {
            float pr = ct * (a.x * cp - a.y * sp) + st * b2.x;
            float pi = ct * (a.x * sp + a.y * cp) + st * b2.y;
            float qr = st * a.x - ct * (b2.x * cp + b2.y * sp);
            float qi = st * a.y - ct * (b2.y * cp - b2.x * sp);
            a = make_float2(pr, pi); b2 = make_float2(qr, qi);
        } else {
            float2 an;
            an.x = __shfl_down(a.x, 1); an.y = __shfl_down(a.y, 1);
            float pr = ct * (b2.x * cp - b2.y * sp) + st * an.x;
            float pi = ct * (b2.x * sp + b2.y * cp) + st * an.y;
            float qr = st * b2.x - ct * (an.x * cp + an.y * sp);
            float qi = st * b2.y - ct * (an.y * cp - an.x * sp);
            if (t < 63) b2 = make_float2(pr, pi);
            float2 qs;
            qs.x = __shfl_up(qr, 1); qs.y = __shfl_up(qi, 1);
            if (t >= 1) a = qs;
        }
    }

    const float* outph = (s == 0) ? outph1 : ((s == 1) ? outph2 : outph3);
    #pragma unroll
    for (int h = 0; h < 2; ++h) {
        const int j = 2 * t + h;
        float2 w = h ? b2 : a;
        float sp, cp; __sincosf(outph[j], &sp, &cp);
        const float wr = w.x * cp - w.y * sp;
        const float wi = w.x * sp + w.y * cp;
        const int cre = ((j >> 4) * 32) + (j & 15);
        if (s == 0) {
            P1[cre * 128 + r]        = f2bf(wr);
            P1[(cre + 16) * 128 + r] = f2bf(wi);
        } else {
            u16* P = (s == 1) ? P2 : P3;
            const int rre = ((r >> 4) * 32) + (r & 15);
            P[cre * 256 + rre]             = f2bf(wr);
            P[cre * 256 + rre + 16]        = f2bf(-wi);
            P[(cre + 16) * 256 + rre]      = f2bf(wi);
            P[(cre + 16) * 256 + rre + 16] = f2bf(wr);
        }
    }
}

// ---------------------------------------------------------------------------
// Combine (R22-proven, ~2-3us): P34[n][k] = sum_c P3[c*256+k] * Wval(n,c).
// Thread t of block n -> (cs = t>>5, kb = (t&31)*8): 32 x {bf16x8 P3 read +
// lane-uniform W read + 8 fmaf}; 8-way LDS reduce over cs + bf16 pack.
// ---------------------------------------------------------------------------
__global__ __launch_bounds__(256) void combine_kernel(
    const u16* __restrict__ P3, const float* __restrict__ W,
    u16* __restrict__ P34)
{
    __shared__ float partial[8][256];
    const int n  = blockIdx.x;     // 0..127 output col
    const int t  = threadIdx.x;
    const int cs = t >> 5;         // 0..7 c-slice
    const int kb = (t & 31) * 8;   // k base

    float acc[8];
    #pragma unroll
    for (int e = 0; e < 8; ++e) acc[e] = 0.f;

    #pragma unroll 4
    for (int cc = 0; cc < 32; ++cc) {
        const int c = cs * 32 + cc;
        const int j = (cc < 16) ? (cs * 16 + cc) : (128 + cs * 16 + (cc - 16));
        const float w = W[n * 256 + j];
        bf16x8 p = *(const bf16x8*)&P3[c * 256 + kb];
        #pragma unroll
        for (int e = 0; e < 8; ++e)
            acc[e] = fmaf(bf2f((unsigned short)p[e]), w, acc[e]);
    }

    #pragma unroll
    for (int e = 0; e < 8; ++e) partial[cs][kb + e] = acc[e];
    __syncthreads();

    if (cs == 0) {
        #pragma unroll
        for (int e = 0; e < 8; ++e) {
            float s = 0.f;
            #pragma unroll
            for (int q = 0; q < 8; ++q) s += partial[q][kb + e];
            P34[n * 256 + kb + e] = f2bf(s);
        }
    }
}

// ---------------------------------------------------------------------------
// Main fused kernel (R22 exact — best proven: bench 75.6us, main 57-64us,
// absmax 0.0117, zero spill/conflicts): 512 threads = 8 narrow waves
// 1M x 8N, wave tile 64x32, 64 rows/block, unroll-2 k-loops, dbuf 2x32KB,
// (512,4), stage 3 fused into P34.
// R23 post-mortem: bundled {native-convert, cross-barrier B-prefetch with
// runtime (ks<2) selector inside the unroll-2 loop} regressed to 81us and
// doubled x-FETCH — the selector breaks the static k-loop scheduling.
// Both reverted; this file is the baseline for any further experiment.
// Phases: stage-x -> B1 -> S1(z0->z1, nofu1) -> B2 -> S2(z1->z0, nofu2)
// -> B3 -> F(z0 -> out via P34).
// ---------------------------------------------------------------------------
__global__ __launch_bounds__(512, 4) void ficonn_mfma_kernel(
    const float* __restrict__ x,
    const u16* __restrict__ P1, const u16* __restrict__ P2,
    const u16* __restrict__ P34,
    const float* __restrict__ al1, const float* __restrict__ be1,
    const float* __restrict__ al2, const float* __restrict__ be2,
    const float* __restrict__ bias, float* __restrict__ out)
{
    __shared__ __align__(16) char zBuf[2][32768];  // [64 rows][256 cols] bf16, swizzled
    char* const z0 = zBuf[0];
    char* const z1 = zBuf[1];

    const int tid  = threadIdx.x;
    const int lane = tid & 63;
    const int wv   = tid >> 6;        // 0..7 (N-split)
    const int l16  = lane & 15;
    const int kg   = lane >> 4;
    const int nb   = wv * 32;         // col base, stages 1-2
    const size_t rowBase = (size_t)blockIdx.x * 64;

    const int jf = wv * 16 + l16;     // this thread's complex feature
    const float av1 = 0.5f * fminf(fmaxf(al1[jf], 0.f), 10.f);
    const float bv1 = fminf(fmaxf(be1[jf], 0.f), 10.f);
    const float av2 = 0.5f * fminf(fmaxf(al2[jf], 0.f), 10.f);
    const float bv2 = fminf(fmaxf(be2[jf], 0.f), 10.f);

    // ---- stage x tile (64 rows x 128 cols fp32) into z0 as bf16, coalesced --
    {
        const float4* xg = (const float4*)(x + rowBase * 128);
        #pragma unroll
        for (int i = 0; i < 4; ++i) {
            const int idx = tid + i * 512;        // 0..2047
            const int row = idx >> 5;             // 32 float4 per row
            const int c4  = idx & 31;
            float4 f = xg[idx];
            uint2 v;
            v.x = (unsigned)f2bf(f.x) | ((unsigned)f2bf(f.y) << 16);
            v.y = (unsigned)f2bf(f.z) | ((unsigned)f2bf(f.w) << 16);
            const unsigned byte = ((unsigned)(row * 512 + c4 * 8)) ^ ((unsigned)(row & 31) << 4);
            *(uint2*)(z0 + byte) = v;
        }
    }
    __syncthreads();    // B1: x staged in z0

    f32x4 acc[4][2];

    // ================= stage 1: read z0 (x), B = P1, K=128 -> write z1 ======
    #pragma unroll
    for (int mt = 0; mt < 4; ++mt)
        #pragma unroll
        for (int nt = 0; nt < 2; ++nt) acc[mt][nt] = (f32x4){0.f, 0.f, 0.f, 0.f};

    #pragma unroll 2
    for (int ksl = 0; ksl < 4; ++ksl) {
        const int k0 = ksl * 32 + kg * 8;
        bf16x8 A[4];
        #pragma unroll
        for (int mt = 0; mt < 4; ++mt) {
            const int row = mt * 16 + l16;
            const unsigned byte = ((unsigned)(row * 512 + k0 * 2)) ^ ((unsigned)(row & 31) << 4);
            A[mt] = *(const bf16x8*)(z0 + byte);
        }
        #pragma unroll
        for (int nt = 0; nt < 2; ++nt) {
            bf16x8 Bf = *(const bf16x8*)&P1[(nb + nt * 16 + l16) * 128 + k0];
            #pragma unroll
            for (int mt = 0; mt < 4; ++mt)
                acc[mt][nt] = __builtin_amdgcn_mfma_f32_16x16x32_bf16(A[mt], Bf, acc[mt][nt], 0, 0, 0);
        }
    }

    // nofu1 + store to z1 (different buffer: no pre-barrier)
    #pragma unroll
    for (int mt = 0; mt < 4; ++mt)
        #pragma unroll
        for (int r = 0; r < 4; ++r) {
            float re = acc[mt][0][r], im = acc[mt][1][r];
            float I = fmaf(re, re, fmaf(im, im, 1e-8f));
            float fct = __expf(__fdividef(-av1, fmaf(bv1, I, 1.f)));
            re *= fct; im *= fct;
            const int row = mt * 16 + kg * 4 + r;
            const int colRe = nb + l16;
            const unsigned sw = (unsigned)(row & 31) << 4;
            *(u16*)(z1 + (((unsigned)(row * 512 + colRe * 2)) ^ sw)) = f2bf(re);
            *(u16*)(z1 + (((unsigned)(row * 512 + (colRe + 16) * 2)) ^ sw)) = f2bf(im);
        }
    __syncthreads();    // B2: z1 complete

    // ================= stage 2: read z1, B = P2, K=256 -> write z0 ==========
    #pragma unroll
    for (int mt = 0; mt < 4; ++mt)
        #pragma unroll
        for (int nt = 0; nt < 2; ++nt) acc[mt][nt] = (f32x4){0.f, 0.f, 0.f, 0.f};

    #pragma unroll 2
    for (int ks = 0; ks < 8; ++ks) {
        const int k0 = ks * 32 + kg * 8;
        bf16x8 A[4];
        #pragma unroll
        for (int mt = 0; mt < 4; ++mt) {
            const int row = mt * 16 + l16;
            const unsigned byte = ((unsigned)(row * 512 + k0 * 2)) ^ ((unsigned)(row & 31) << 4);
            A[mt] = *(const bf16x8*)(z1 + byte);
        }
        #pragma unroll
        for (int nt = 0; nt < 2; ++nt) {
            bf16x8 Bf = *(const bf16x8*)&P2[(nb + nt * 16 + l16) * 256 + k0];
            #pragma unroll
            for (int mt = 0; mt < 4; ++mt)
                acc[mt][nt] = __builtin_amdgcn_mfma_f32_16x16x32_bf16(A[mt], Bf, acc[mt][nt], 0, 0, 0);
        }
    }

    // nofu2 + store to z0
    #pragma unroll
    for (int mt = 0; mt < 4; ++mt)
        #pragma unroll
        for (int r = 0; r < 4; ++r) {
            float re = acc[mt][0][r], im = acc[mt][1][r];
            float I = fmaf(re, re, fmaf(im, im, 1e-8f));
            float fct = __expf(__fdividef(-av2, fmaf(bv2, I, 1.f)));
            re *= fct; im *= fct;
            const int row = mt * 16 + kg * 4 + r;
            const int colRe = nb + l16;
            const unsigned sw = (unsigned)(row & 31) << 4;
            *(u16*)(z0 + (((unsigned)(row * 512 + colRe * 2)) ^ sw)) = f2bf(re);
            *(u16*)(z0 + (((unsigned)(row * 512 + (colRe + 16) * 2)) ^ sw)) = f2bf(im);
        }
    __syncthreads();    // B3: z0 complete

    // ================= final: read z0, B = P34 [128 cols][256 k] ============
    f32x4 facc[4];
    #pragma unroll
    for (int mt = 0; mt < 4; ++mt) facc[mt] = (f32x4){0.f, 0.f, 0.f, 0.f};

    const int nb2 = wv * 16;
    #pragma unroll 2
    for (int ks = 0; ks < 8; ++ks) {
        const int k0 = ks * 32 + kg * 8;
        bf16x8 A[4];
        #pragma unroll
        for (int mt = 0; mt < 4; ++mt) {
            const int row = mt * 16 + l16;
            const unsigned byte = ((unsigned)(row * 512 + k0 * 2)) ^ ((unsigned)(row & 31) << 4);
            A[mt] = *(const bf16x8*)(z0 + byte);
        }
        bf16x8 Bf = *(const bf16x8*)&P34[(nb2 + l16) * 256 + k0];
        #pragma unroll
        for (int mt = 0; mt < 4; ++mt)
            facc[mt] = __builtin_amdgcn_mfma_f32_16x16x32_bf16(A[mt], Bf, facc[mt], 0, 0, 0);
    }

    const float bcol = bias[nb2 + l16];
    #pragma unroll
    for (int mt = 0; mt < 4; ++mt)
        #pragma unroll
        for (int r = 0; r < 4; ++r) {
            const size_t row = rowBase + mt * 16 + kg * 4 + r;
            out[row * 128 + nb2 + l16] = facc[mt][r] + bcol;
        }
}

extern "C" void kernel_launch(void* const* d_in, const int* in_sizes, int n_in,
                              void* d_out, int out_size, void* d_ws, size_t ws_size,
                              hipStream_t stream)
{
    const float* x      = (const float*)d_in[0];
    const float* inph   = (const float*)d_in[1];
    const float* mzi1   = (const float*)d_in[2];
    const float* outph1 = (const float*)d_in[3];
    const float* alpha1 = (const float*)d_in[4];
    const float* beta1  = (const float*)d_in[5];
    const float* mzi2   = (const float*)d_in[6];
    const float* outph2 = (const float*)d_in[7];
    const float* alpha2 = (const float*)d_in[8];
    const float* beta2  = (const float*)d_in[9];
    const float* mzi3   = (const float*)d_in[10];
    const float* outph3 = (const float*)d_in[11];
    const float* W      = (const float*)d_in[12];
    const float* bias   = (const float*)d_in[13];

    const int B = in_sizes[0] / 128;

    // ws layout: P1 64KB | P2 128KB | P3 128KB | P34 64KB = 384KB
    u16* P1  = (u16*)d_ws;
    u16* P2  = P1 + 32768;
    u16* P3  = P2 + 65536;
    u16* P34 = P3 + 65536;

    prep_all_kernel<<<384, 128, 0, stream>>>(
        mzi1, mzi2, mzi3, inph, outph1, outph2, outph3, P1, P2, P3);
    combine_kernel<<<128, 256, 0, stream>>>(P3, W, P34);
    ficonn_mfma_kernel<<<B / 64, 512, 0, stream>>>(
        x, P1, P2, P34, alpha1, beta1, alpha2, beta2, bias, (float*)d_out);
}